// Round 1
// baseline (114.914 us; speedup 1.0000x reference)
//
#include <hip/hip_runtime.h>
#include <stdint.h>

#define S_LEN 2048
#define EMB 1024
#define NHEADS 16
#define HDIM 64

typedef __bf16 bf16x8 __attribute__((ext_vector_type(8)));
typedef float f32x4 __attribute__((ext_vector_type(4)));

__device__ __forceinline__ unsigned short f2bf(float f) {
  unsigned int b = __float_as_uint(f);
  b += 0x7FFFu + ((b >> 16) & 1u);
  return (unsigned short)(b >> 16);
}

#define GLD16(gp, lp)                                                          \
  __builtin_amdgcn_global_load_lds(                                            \
      (const __attribute__((address_space(1))) void*)(gp),                     \
      (__attribute__((address_space(3))) void*)(lp), 16, 0, 0)

// ---------------------------------------------------------------------------
// Kernel 1: per-(n,s) 16x16 head-Gram attention. One wave (64 threads) per
// position. Writes the reshaped intermediate X[(n*2048 + i*128 + s/16)][ (s%16)*64 + d ]
// as bf16 bits into workspace.
// ---------------------------------------------------------------------------
__global__ __launch_bounds__(64) void attn_kernel(
    const float* __restrict__ Q, const float* __restrict__ K,
    const float* __restrict__ V, const int* __restrict__ mask,
    unsigned short* __restrict__ X) {
  const int pos = blockIdx.x;      // 0..16383
  const int n = pos >> 11;         // /2048
  const int s = pos & 2047;
  const int lane = threadIdx.x;    // 0..63

  __shared__ float Qs[16][68];     // padded rows: head i, d 0..63
  __shared__ float Ks[16][68];
  __shared__ float Vs[1024];
  __shared__ float As[16][17];     // attention weights

  const float* qrow = Q + (size_t)pos * EMB;
  const float* krow = K + (size_t)pos * EMB;
  const float* vrow = V + (size_t)pos * EMB;

#pragma unroll
  for (int c = 0; c < 4; ++c) {
    int e = c * 256 + lane * 4;
    float4 qv = *(const float4*)(qrow + e);
    float4 kv = *(const float4*)(krow + e);
    float4 vv = *(const float4*)(vrow + e);
    int i = e >> 6, d = e & 63;
    *(float4*)&Qs[i][d] = qv;
    *(float4*)&Ks[i][d] = kv;
    *(float4*)&Vs[e] = vv;
  }
  __syncthreads();

  const int i2 = lane >> 4;  // 0..3
  const int j = lane & 15;   // key-head index
  float p[4];
#pragma unroll
  for (int t = 0; t < 4; ++t) {
    const int i = t * 4 + i2;  // query-head index
    float acc = 0.f;
#pragma unroll
    for (int dc = 0; dc < 16; ++dc) {
      float4 qv = *(const float4*)&Qs[i][dc * 4];
      float4 kv = *(const float4*)&Ks[j][dc * 4];
      acc += qv.x * kv.x + qv.y * kv.y + qv.z * kv.z + qv.w * kv.w;
    }
    float g = acc * 0.125f;                     // 1/sqrt(64)
    if (mask[i * 16 + j] == 0) g = -1e30f;      // effectively -inf
    // softmax over j: reduce within 16-lane groups
    float mx = g;
#pragma unroll
    for (int off = 1; off < 16; off <<= 1) mx = fmaxf(mx, __shfl_xor(mx, off));
    float ex = __expf(g - mx);
    float sm = ex;
#pragma unroll
    for (int off = 1; off < 16; off <<= 1) sm += __shfl_xor(sm, off);
    p[t] = ex / sm;
  }
#pragma unroll
  for (int t = 0; t < 4; ++t) As[t * 4 + i2][j] = p[t];
  __syncthreads();

  // O[i][d] = sum_j A[i][j] * V[j*64+d]; lane owns d = lane.
  // X row (within batch) = i*128 + s/16 ; col = (s%16)*64 + d
  const size_t xbase =
      ((size_t)n * S_LEN + (s >> 4)) * EMB + (size_t)((s & 15) * HDIM + lane);
  for (int i = 0; i < 16; ++i) {
    float acc = 0.f;
#pragma unroll
    for (int jj = 0; jj < 16; ++jj) acc += As[i][jj] * Vs[jj * 64 + lane];
    X[xbase + (size_t)i * 128 * EMB] = f2bf(acc);
  }
}

// ---------------------------------------------------------------------------
// Kernel 2: W_out fp32 -> bf16 bits
// ---------------------------------------------------------------------------
__global__ __launch_bounds__(256) void wconv_kernel(
    const float* __restrict__ W, unsigned short* __restrict__ Wb) {
  const int idx = blockIdx.x * 256 + threadIdx.x;  // 262144 threads, 4 each
  float4 w = *(const float4*)(W + (size_t)idx * 4);
  ushort4 o;
  o.x = f2bf(w.x);
  o.y = f2bf(w.y);
  o.z = f2bf(w.z);
  o.w = f2bf(w.w);
  *(ushort4*)(Wb + (size_t)idx * 4) = o;
}

// ---------------------------------------------------------------------------
// Kernel 3: C[M=16384][N=1024] = A[M][K=1024] * B[N][K]^T + bias
// m97 structure: 128x128 tile, BK=32, 4 waves (2x2), 16x16x32 bf16 MFMA,
// global_load_lds width-16 staging, single-buffered LDS.
// ---------------------------------------------------------------------------
__global__ __launch_bounds__(256) void gemm_kernel(
    const unsigned short* __restrict__ A, const unsigned short* __restrict__ B,
    const float* __restrict__ bias, float* __restrict__ C) {
  __shared__ unsigned short sA[128 * 32];
  __shared__ unsigned short sB[128 * 32];

  // XCD-aware bijective swizzle (nwg = 1024, divisible by 8)
  int bid = blockIdx.x;
  const int cpx = gridDim.x >> 3;
  bid = (bid & 7) * cpx + (bid >> 3);
  const int tileM = (bid >> 3) * 128;  // 128 m-tiles
  const int tileN = (bid & 7) * 128;   // 8 n-tiles

  const int t = threadIdx.x;
  const int lane = t & 63;
  const int wid = t >> 6;
  const int wm = wid >> 1, wn = wid & 1;
  const int lrow = lane & 15;
  const int lgrp = lane >> 4;

  f32x4 acc[4][4];
#pragma unroll
  for (int a = 0; a < 4; ++a)
#pragma unroll
    for (int b = 0; b < 4; ++b) acc[a][b] = (f32x4){0.f, 0.f, 0.f, 0.f};

  // staging: lds byte offset o = c*4096 + t*16 ; row = o/64 ; k = (o%64)/2
  const int row0 = t >> 2;
  const int kk = (t & 3) * 8;
  const size_t abase = ((size_t)(tileM + row0)) * 1024 + kk;
  const size_t bbase = ((size_t)(tileN + row0)) * 1024 + kk;

  for (int k0 = 0; k0 < 1024; k0 += 32) {
#pragma unroll
    for (int c = 0; c < 2; ++c) {
      GLD16(A + abase + (size_t)c * 64 * 1024 + k0,
            (char*)sA + c * 4096 + t * 16);
      GLD16(B + bbase + (size_t)c * 64 * 1024 + k0,
            (char*)sB + c * 4096 + t * 16);
    }
    __syncthreads();

    bf16x8 af[4], bfr[4];
#pragma unroll
    for (int mi = 0; mi < 4; ++mi)
      af[mi] = *(const bf16x8*)&sA[(wm * 64 + mi * 16 + lrow) * 32 + lgrp * 8];
#pragma unroll
    for (int ni = 0; ni < 4; ++ni)
      bfr[ni] = *(const bf16x8*)&sB[(wn * 64 + ni * 16 + lrow) * 32 + lgrp * 8];
#pragma unroll
    for (int mi = 0; mi < 4; ++mi)
#pragma unroll
      for (int ni = 0; ni < 4; ++ni)
        acc[mi][ni] = __builtin_amdgcn_mfma_f32_16x16x32_bf16(
            af[mi], bfr[ni], acc[mi][ni], 0, 0, 0);
    __syncthreads();
  }

  // epilogue: C/D layout col = lane&15, row = (lane>>4)*4 + reg
#pragma unroll
  for (int ni = 0; ni < 4; ++ni) {
    const int col = tileN + wn * 64 + ni * 16 + lrow;
    const float bv = bias[col];
#pragma unroll
    for (int mi = 0; mi < 4; ++mi) {
      const int row = tileM + wm * 64 + mi * 16 + lgrp * 4;
#pragma unroll
      for (int r = 0; r < 4; ++r)
        C[(size_t)(row + r) * 1024 + col] = acc[mi][ni][r] + bv;
    }
  }
}

// ---------------------------------------------------------------------------
extern "C" void kernel_launch(void* const* d_in, const int* in_sizes, int n_in,
                              void* d_out, int out_size, void* d_ws,
                              size_t ws_size, hipStream_t stream) {
  const float* Q = (const float*)d_in[0];
  const float* K = (const float*)d_in[1];
  const float* V = (const float*)d_in[2];
  const int* mask = (const int*)d_in[3];
  const float* W = (const float*)d_in[4];
  const float* bias = (const float*)d_in[5];
  float* out = (float*)d_out;

  unsigned short* X = (unsigned short*)d_ws;  // 16384x1024 bf16 = 32 MB
  unsigned short* Wb =
      (unsigned short*)((char*)d_ws + (size_t)32 * 1024 * 1024);  // 2 MB

  hipLaunchKernelGGL(attn_kernel, dim3(8 * S_LEN), dim3(64), 0, stream, Q, K,
                     V, mask, X);
  hipLaunchKernelGGL(wconv_kernel, dim3(1024), dim3(256), 0, stream, W, Wb);
  hipLaunchKernelGGL(gemm_kernel, dim3(1024), dim3(256), 0, stream, X, Wb,
                     bias, out);
}

// Round 2
// 99.147 us; speedup vs baseline: 1.1590x; 1.1590x over previous
//
#include <hip/hip_runtime.h>
#include <stdint.h>

#define S_LEN 2048
#define EMB 1024

typedef __bf16 bf16x8 __attribute__((ext_vector_type(8)));
typedef float f32x4 __attribute__((ext_vector_type(4)));

__device__ __forceinline__ unsigned short f2bf(float f) {
  unsigned int b = __float_as_uint(f);
  b += 0x7FFFu + ((b >> 16) & 1u);
  return (unsigned short)(b >> 16);
}

__device__ __forceinline__ bf16x8 cvt8(float4 a, float4 b) {
  bf16x8 r;
  r[0] = (__bf16)a.x; r[1] = (__bf16)a.y; r[2] = (__bf16)a.z; r[3] = (__bf16)a.w;
  r[4] = (__bf16)b.x; r[5] = (__bf16)b.y; r[6] = (__bf16)b.z; r[7] = (__bf16)b.w;
  return r;
}

#define GLD16(gp, lp)                                                          \
  __builtin_amdgcn_global_load_lds(                                            \
      (const __attribute__((address_space(1))) void*)(gp),                     \
      (__attribute__((address_space(3))) void*)(lp), 16, 0, 0)

// ---------------------------------------------------------------------------
// Kernel 1: per-(n,s) 16x16 head-Gram attention, MFMA-based, barrier-free.
// One wave per position, 4 waves per block. Writes reshaped X as bf16.
// ---------------------------------------------------------------------------
__global__ __launch_bounds__(256) void attn_kernel(
    const float* __restrict__ Q, const float* __restrict__ K,
    const float* __restrict__ V, const int* __restrict__ mask,
    __bf16* __restrict__ X) {
  __shared__ __bf16 Vt[4][64][24];  // V transposed: [d][head], padded rows
  __shared__ __bf16 As[4][16][24];  // attention weights, padded rows

  const int lane = threadIdx.x & 63;
  const int wv = threadIdx.x >> 6;
  const int pos = blockIdx.x * 4 + wv;  // 0..16383
  const int n = pos >> 11;
  const int s = pos & 2047;
  const int j16 = lane & 15;
  const int grp = lane >> 4;

  const float* qrow = Q + (size_t)pos * EMB;
  const float* krow = K + (size_t)pos * EMB;
  const float* vrow = V + (size_t)pos * EMB;

  // --- stage V transposed into LDS as bf16 (coalesced read, scatter write) ---
#pragma unroll
  for (int c = 0; c < 4; ++c) {
    const int e = c * 256 + lane * 4;
    const float4 vv = *(const float4*)(vrow + e);
    const int hi = e >> 6;   // head index 0..15
    const int d0 = e & 63;   // dim 0..63 (multiple of 4)
    Vt[wv][d0 + 0][hi] = (__bf16)vv.x;
    Vt[wv][d0 + 1][hi] = (__bf16)vv.y;
    Vt[wv][d0 + 2][hi] = (__bf16)vv.z;
    Vt[wv][d0 + 3][hi] = (__bf16)vv.w;
  }

  // --- Q/K MFMA fragments direct from global (row l&15, k-slice (l>>4)*8) ---
  const int fo = j16 * 64 + grp * 8;
  bf16x8 qa[2], kb[2];
#pragma unroll
  for (int t = 0; t < 2; ++t) {
    float4 a0 = *(const float4*)(qrow + fo + t * 32);
    float4 a1 = *(const float4*)(qrow + fo + t * 32 + 4);
    float4 b0 = *(const float4*)(krow + fo + t * 32);
    float4 b1 = *(const float4*)(krow + fo + t * 32 + 4);
    qa[t] = cvt8(a0, a1);
    kb[t] = cvt8(b0, b1);
  }

  // --- energy = Q(16x64) . K^T : two K=32 MFMAs ---
  f32x4 en = {0.f, 0.f, 0.f, 0.f};
  en = __builtin_amdgcn_mfma_f32_16x16x32_bf16(qa[0], kb[0], en, 0, 0, 0);
  en = __builtin_amdgcn_mfma_f32_16x16x32_bf16(qa[1], kb[1], en, 0, 0, 0);
  // lane holds energy[i = grp*4+r][j = j16]

  // --- mask + softmax over j (16-lane groups) ---
  float p[4];
#pragma unroll
  for (int r = 0; r < 4; ++r) {
    const int i = grp * 4 + r;
    float g = en[r] * 0.125f;
    if (mask[i * 16 + j16] == 0) g = -1e30f;
    p[r] = g;
  }
#pragma unroll
  for (int off = 1; off < 16; off <<= 1) {
#pragma unroll
    for (int r = 0; r < 4; ++r) {
      float o = __shfl_xor(p[r], off);
      // first phase: compute max into separate regs
      (void)o;
    }
  }
  // (explicit two-phase reduce below; loop above removed by compiler)
  float mx[4], ex[4], sm[4];
#pragma unroll
  for (int r = 0; r < 4; ++r) mx[r] = p[r];
#pragma unroll
  for (int off = 1; off < 16; off <<= 1)
#pragma unroll
    for (int r = 0; r < 4; ++r) mx[r] = fmaxf(mx[r], __shfl_xor(mx[r], off));
#pragma unroll
  for (int r = 0; r < 4; ++r) {
    ex[r] = __expf(p[r] - mx[r]);
    sm[r] = ex[r];
  }
#pragma unroll
  for (int off = 1; off < 16; off <<= 1)
#pragma unroll
    for (int r = 0; r < 4; ++r) sm[r] += __shfl_xor(sm[r], off);
#pragma unroll
  for (int r = 0; r < 4; ++r) {
    const float inv = __builtin_amdgcn_rcpf(sm[r]);
    As[wv][grp * 4 + r][j16] = (__bf16)(ex[r] * inv);
  }

  // --- A-frag for PV: lane reads A[row j16][k = grp*8..+7], zero for k>=16 ---
  bf16x8 af;
#pragma unroll
  for (int e = 0; e < 8; ++e) af[e] = (__bf16)0.f;
  if (grp < 2) af = *(const bf16x8*)&As[wv][j16][grp * 8];

  // --- PV: O(16x64) = A(16x16,pad32) x V(16x64), 4 N-chunks of 16 ---
  const size_t xbase =
      ((size_t)n * S_LEN + (s >> 4)) * EMB + (size_t)((s & 15) * 64);
  __bf16* xp = X + xbase + j16 + (size_t)grp * 4 * 128 * EMB;
#pragma unroll
  for (int c = 0; c < 4; ++c) {
    bf16x8 bv;
#pragma unroll
    for (int e = 0; e < 8; ++e) bv[e] = (__bf16)0.f;
    if (grp < 2) bv = *(const bf16x8*)&Vt[wv][c * 16 + j16][grp * 8];
    f32x4 o = {0.f, 0.f, 0.f, 0.f};
    o = __builtin_amdgcn_mfma_f32_16x16x32_bf16(af, bv, o, 0, 0, 0);
    // lane holds O[i = grp*4+r][d = c*16 + j16]
#pragma unroll
    for (int r = 0; r < 4; ++r)
      xp[(size_t)r * 128 * EMB + c * 16] = (__bf16)o[r];
  }
}

// ---------------------------------------------------------------------------
// Kernel 2: W_out fp32 -> bf16 bits
// ---------------------------------------------------------------------------
__global__ __launch_bounds__(256) void wconv_kernel(
    const float* __restrict__ W, unsigned short* __restrict__ Wb) {
  const int idx = blockIdx.x * 256 + threadIdx.x;
  float4 w = *(const float4*)(W + (size_t)idx * 4);
  ushort4 o;
  o.x = f2bf(w.x);
  o.y = f2bf(w.y);
  o.z = f2bf(w.z);
  o.w = f2bf(w.w);
  *(ushort4*)(Wb + (size_t)idx * 4) = o;
}

// ---------------------------------------------------------------------------
// Kernel 3: C[16384][1024] = X[16384][1024] * W[1024][1024]^T + bias
// ---------------------------------------------------------------------------
__global__ __launch_bounds__(256) void gemm_kernel(
    const unsigned short* __restrict__ A, const unsigned short* __restrict__ B,
    const float* __restrict__ bias, float* __restrict__ C) {
  __shared__ unsigned short sA[128 * 32];
  __shared__ unsigned short sB[128 * 32];

  int bid = blockIdx.x;
  const int cpx = gridDim.x >> 3;
  bid = (bid & 7) * cpx + (bid >> 3);
  const int tileM = (bid >> 3) * 128;
  const int tileN = (bid & 7) * 128;

  const int t = threadIdx.x;
  const int lane = t & 63;
  const int wid = t >> 6;
  const int wm = wid >> 1, wn = wid & 1;
  const int lrow = lane & 15;
  const int lgrp = lane >> 4;

  f32x4 acc[4][4];
#pragma unroll
  for (int a = 0; a < 4; ++a)
#pragma unroll
    for (int b = 0; b < 4; ++b) acc[a][b] = (f32x4){0.f, 0.f, 0.f, 0.f};

  const int row0 = t >> 2;
  const int kk = (t & 3) * 8;
  const size_t abase = ((size_t)(tileM + row0)) * 1024 + kk;
  const size_t bbase = ((size_t)(tileN + row0)) * 1024 + kk;

  for (int k0 = 0; k0 < 1024; k0 += 32) {
#pragma unroll
    for (int c = 0; c < 2; ++c) {
      GLD16(A + abase + (size_t)c * 64 * 1024 + k0,
            (char*)sA + c * 4096 + t * 16);
      GLD16(B + bbase + (size_t)c * 64 * 1024 + k0,
            (char*)sB + c * 4096 + t * 16);
    }
    __syncthreads();

    bf16x8 af[4], bfr[4];
#pragma unroll
    for (int mi = 0; mi < 4; ++mi)
      af[mi] = *(const bf16x8*)&sA[(wm * 64 + mi * 16 + lrow) * 32 + lgrp * 8];
#pragma unroll
    for (int ni = 0; ni < 4; ++ni)
      bfr[ni] = *(const bf16x8*)&sB[(wn * 64 + ni * 16 + lrow) * 32 + lgrp * 8];
#pragma unroll
    for (int mi = 0; mi < 4; ++mi)
#pragma unroll
      for (int ni = 0; ni < 4; ++ni)
        acc[mi][ni] = __builtin_amdgcn_mfma_f32_16x16x32_bf16(
            af[mi], bfr[ni], acc[mi][ni], 0, 0, 0);
    __syncthreads();
  }

#pragma unroll
  for (int ni = 0; ni < 4; ++ni) {
    const int col = tileN + wn * 64 + ni * 16 + lrow;
    const float bv = bias[col];
#pragma unroll
    for (int mi = 0; mi < 4; ++mi) {
      const int row = tileM + wm * 64 + mi * 16 + lgrp * 4;
#pragma unroll
      for (int r = 0; r < 4; ++r)
        C[(size_t)(row + r) * 1024 + col] = acc[mi][ni][r] + bv;
    }
  }
}

// ---------------------------------------------------------------------------
extern "C" void kernel_launch(void* const* d_in, const int* in_sizes, int n_in,
                              void* d_out, int out_size, void* d_ws,
                              size_t ws_size, hipStream_t stream) {
  const float* Q = (const float*)d_in[0];
  const float* K = (const float*)d_in[1];
  const float* V = (const float*)d_in[2];
  const int* mask = (const int*)d_in[3];
  const float* W = (const float*)d_in[4];
  const float* bias = (const float*)d_in[5];
  float* out = (float*)d_out;

  __bf16* X = (__bf16*)d_ws;  // 16384x1024 bf16 = 32 MB
  unsigned short* Wb =
      (unsigned short*)((char*)d_ws + (size_t)32 * 1024 * 1024);  // 2 MB

  hipLaunchKernelGGL(attn_kernel, dim3(8 * S_LEN / 4), dim3(256), 0, stream, Q,
                     K, V, mask, X);
  hipLaunchKernelGGL(wconv_kernel, dim3(1024), dim3(256), 0, stream, W, Wb);
  hipLaunchKernelGGL(gemm_kernel, dim3(1024), dim3(256), 0, stream,
                     (const unsigned short*)X, Wb, bias, out);
}